// Round 18
// baseline (172.937 us; speedup 1.0000x reference)
//
#include <hip/hip_runtime.h>

// Problem constants: B=8, M=N=256, D=512
#define INFV 1.0e8f
#define USTR 192   // pair-planes per batch: u = (row>>1) + lane, 0..190, pad 192

// Raw HW transcendentals: v_exp_f32 is 2^x, v_log_f32 is log2(x).
#define EXP2F(x) __builtin_amdgcn_exp2f(x)
#define LOG2F(x) __builtin_amdgcn_logf(x)

__device__ __forceinline__ void ld4(float d[4], const float* p) {
  float4 v = *(const float4*)p;
  d[0] = v.x; d[1] = v.y; d[2] = v.z; d[3] = v.w;
}

// ---------------------------------------------------------------------------
// Kernel 1: inverse row norms.  rn = 1 / max(||row||, 1e-8)
// ---------------------------------------------------------------------------
__global__ void __launch_bounds__(256) norms_kernel(const float* __restrict__ x,
                                                    const float* __restrict__ y,
                                                    float* __restrict__ rnx,
                                                    float* __restrict__ rny) {
  int g = blockIdx.x * 4 + (threadIdx.x >> 6);
  int lane = threadIdx.x & 63;
  const float* src; float* dst; int row;
  if (g < 2048) { src = x; dst = rnx; row = g; }
  else          { src = y; dst = rny; row = g - 2048; }
  const float* p = src + (size_t)row * 512;
  float4 v0 = *(const float4*)(p + lane * 4);
  float4 v1 = *(const float4*)(p + 256 + lane * 4);
  float s = v0.x*v0.x + v0.y*v0.y + v0.z*v0.z + v0.w*v0.w
          + v1.x*v1.x + v1.y*v1.y + v1.z*v1.z + v1.w*v1.w;
#pragma unroll
  for (int o = 32; o > 0; o >>= 1) s += __shfl_xor(s, o, 64);
  if (lane == 0) dst[row] = 1.0f / fmaxf(sqrtf(s), 1e-8f);
}

// ---------------------------------------------------------------------------
// Kernel 2: cost GEMM, 32x64 tiles (256 blocks).  Outputs:
//   costR[b][m][n] = cost*ig2            row-major (weights kernel)
//   mD2 pair-planes: plane u = (m>>1)+l holds, per lane l, the 2x4 record
//     {exp2(-csc) rows 2v..2v+1, cols 4l..4l+3} at offset l*8 -- the fwd
//     kernel reads plane u coalesced.  Each thread's 2x4 micro-tile is
//     exactly one record (8 contiguous floats).
// ---------------------------------------------------------------------------
__global__ void __launch_bounds__(256) cost_gemm(const float* __restrict__ x,
                                                 const float* __restrict__ y,
                                                 const float* __restrict__ rnx,
                                                 const float* __restrict__ rny,
                                                 const float* __restrict__ gamma,
                                                 float* __restrict__ costR,
                                                 float* __restrict__ mD2) {
  int b = blockIdx.z, mt = blockIdx.y, nt = blockIdx.x;
  int m0 = mt * 32, n0 = nt * 64;
  __shared__ float Xs[16][36];
  __shared__ float Ys[16][68];
  int tid = threadIdx.x;
  int row = tid >> 2, cq = tid & 3;
  int tx = tid & 15, ty = tid >> 4;
  const float* xb = x + ((size_t)b * 256 + m0) * 512;
  const float* yb = y + ((size_t)b * 256 + n0) * 512;
  float acc[2][4] = {};
  for (int k0 = 0; k0 < 512; k0 += 16) {
    float4 xv;
    if (tid < 128) xv = *(const float4*)(xb + (size_t)row * 512 + k0 + cq * 4);
    float4 yv = *(const float4*)(yb + (size_t)row * 512 + k0 + cq * 4);
    __syncthreads();
    if (tid < 128) {
      Xs[cq*4+0][row] = xv.x; Xs[cq*4+1][row] = xv.y;
      Xs[cq*4+2][row] = xv.z; Xs[cq*4+3][row] = xv.w;
    }
    Ys[cq*4+0][row] = yv.x; Ys[cq*4+1][row] = yv.y;
    Ys[cq*4+2][row] = yv.z; Ys[cq*4+3][row] = yv.w;
    __syncthreads();
#pragma unroll
    for (int kk = 0; kk < 16; ++kk) {
      float a0 = Xs[kk][ty * 2 + 0];
      float a1 = Xs[kk][ty * 2 + 1];
      float4 bv = *(const float4*)(&Ys[kk][tx * 4]);
      float br[4] = {bv.x, bv.y, bv.z, bv.w};
#pragma unroll
      for (int c = 0; c < 4; ++c) {
        acc[0][c] += a0 * br[c];
        acc[1][c] += a1 * br[c];
      }
    }
  }
  float gv = fmaxf(fabsf(gamma[0]), 1e-4f);
  float ig2 = 1.4426950408889634f / gv;
  float rx[2], ry[4];
#pragma unroll
  for (int r = 0; r < 2; ++r) rx[r] = rnx[b * 256 + m0 + ty * 2 + r];
#pragma unroll
  for (int c = 0; c < 4; ++c) ry[c] = rny[b * 256 + n0 + tx * 4 + c];
  float* cbb = costR + (size_t)b * 65536;
  int l = nt * 16 + tx;                  // column-group lane
  int u = (mt * 16 + ty) + l;            // pair-plane index
  float4 stm[2];
#pragma unroll
  for (int r = 0; r < 2; ++r) {
    int m = m0 + ty * 2 + r;
    float c0 = (1.0f - acc[r][0] * rx[r] * ry[0]) * ig2;
    float c1 = (1.0f - acc[r][1] * rx[r] * ry[1]) * ig2;
    float c2 = (1.0f - acc[r][2] * rx[r] * ry[2]) * ig2;
    float c3 = (1.0f - acc[r][3] * rx[r] * ry[3]) * ig2;
    float4 stc = {c0, c1, c2, c3};
    *(float4*)(cbb + (size_t)m * 256 + n0 + tx * 4) = stc;
    stm[r] = (float4){EXP2F(-c0), EXP2F(-c1), EXP2F(-c2), EXP2F(-c3)};
  }
  float* mp = mD2 + ((size_t)b * USTR + u) * 512 + l * 8;
  *(float4*)(mp) = stm[0];
  *(float4*)(mp + 4) = stm[1];
}

// ---------------------------------------------------------------------------
// Kernel 3: forward soft-DTW, P-DOMAIN, 2 ROWS PER SLOT.  One wave per batch.
// Lane l owns cols 4l..4l+3; at slot t processes rows R=2(t-l), R+1 (active
// iff 0 <= t-l <= 127) -- 192 slots (was 336).  Plane u = t: cost read and
// P store are coalesced 2 KB transactions.  p = P * 2^Q, Q constant per
// 8-slot (16-row) epoch; cross-lane: shfl of the two col-(4l-1) values + Q.
// q reconstructed later as -Qep - log2(P).
// ---------------------------------------------------------------------------
__global__ void __launch_bounds__(64, 1) fwd_kernel(const float* __restrict__ mD2,
                                                    const float* __restrict__ gamma,
                                                    float* __restrict__ pD2,
                                                    float* __restrict__ Qep,
                                                    float* __restrict__ dist_out) {
  int b = blockIdx.x, l = threadIdx.x;
  float gv = fmaxf(fabsf(gamma[0]), 1e-4f);
  float gl = gv * 0.6931471805599453f;      // R = q * gl
  const float* mb = mD2 + (size_t)b * USTR * 512 + l * 8;
  float* pb = pD2 + (size_t)b * USTR * 512 + l * 8;
  float* qe = Qep + ((size_t)b * 64 + l) * 24;   // 24 epochs
  float Pp0 = 0.f, Pp1 = 0.f, Pp2 = 0.f, Pp3 = 0.f;  // row R-1 (own, scaled)
  float bot0 = 0.f, bot1 = 0.f;   // my col-3 values of last pair (for lane l+1)
  int Q = 0;                       // lane scale: p = P * 2^Q
  float ucar = (l == 0) ? 1.0f : 0.f;  // p(R-1, 4l-1); origin seed p(-1,-1)=1
  float A0[8], A1[8], A2[8], A3[8], A4[8], A5[8], A6[8], A7[8];
  float A8[8], A9[8], A10[8], A11[8], A12[8], A13[8], A14[8], A15[8];
  auto loadC = [&](int t, float* buf) {
    int u = t > 190 ? 190 : t;
    const float* p = mb + (size_t)u * 512;
    ld4(buf, p); ld4(buf + 4, p + 4);
  };
  auto body = [&](int t, const float* mm) {
    bool act = (unsigned)(t - l) <= 127u;
    float s0 = __shfl_up(bot0, 1);   // p(R,   4l-1) from lane l-1
    float s1 = __shfl_up(bot1, 1);   // p(R+1, 4l-1)
    int  liQ = __shfl_up(Q, 1);
    if (l == 0) { s0 = 0.f; s1 = 0.f; }
    else { int adj = liQ - Q; s0 = ldexpf(s0, adj); s1 = ldexpf(s1, adj); }
    // row R
    float v0 = mm[0] * (Pp0 + s0 + ucar);
    float v1 = mm[1] * (Pp1 + v0 + Pp0);
    float v2 = mm[2] * (Pp2 + v1 + Pp1);
    float v3 = mm[3] * (Pp3 + v2 + Pp2);
    // row R+1
    float w0 = mm[4] * (v0 + s1 + s0);
    float w1 = mm[5] * (v1 + w0 + v0);
    float w2 = mm[6] * (v2 + w1 + v1);
    float w3 = mm[7] * (v3 + w2 + v2);
    if (act) {
      float* sp = pb + (size_t)t * 512;
      *(float4*)(sp)     = (float4){v0, v1, v2, v3};
      *(float4*)(sp + 4) = (float4){w0, w1, w2, w3};
      Pp0 = w0; Pp1 = w1; Pp2 = w2; Pp3 = w3;
      ucar = s1; bot0 = v3; bot1 = w3;
      if (l == 63 && t == 190)
        dist_out[b] = (-(float)Q - LOG2F(w3)) * gl;
    }
  };
  auto renorm = [&](int tEnd) {
    if ((unsigned)(tEnd - l) <= 127u) {
      int e = (int)((__float_as_uint(Pp3) >> 23) & 255u) - 127;
      Pp0 = ldexpf(Pp0, -e); Pp1 = ldexpf(Pp1, -e);
      Pp2 = ldexpf(Pp2, -e); Pp3 = ldexpf(Pp3, -e);
      ucar = ldexpf(ucar, -e);
      bot0 = ldexpf(bot0, -e); bot1 = ldexpf(bot1, -e);
      Q += e;
    }
  };
  loadC(0, A0);  loadC(1, A1);  loadC(2, A2);  loadC(3, A3);
  loadC(4, A4);  loadC(5, A5);  loadC(6, A6);  loadC(7, A7);
  loadC(8, A8);  loadC(9, A9);  loadC(10, A10); loadC(11, A11);
  loadC(12, A12); loadC(13, A13); loadC(14, A14); loadC(15, A15);
  for (int it = 0; it < 12; ++it) {   // 12 x 16 = 192 slots; last live 190
    int s = it * 16;
    qe[2 * it] = (float)Q;
    body(s + 0, A0); loadC(s + 16, A0);
    body(s + 1, A1); loadC(s + 17, A1);
    body(s + 2, A2); loadC(s + 18, A2);
    body(s + 3, A3); loadC(s + 19, A3);
    body(s + 4, A4); loadC(s + 20, A4);
    body(s + 5, A5); loadC(s + 21, A5);
    body(s + 6, A6); loadC(s + 22, A6);
    body(s + 7, A7); loadC(s + 23, A7);
    renorm(s + 7);
    qe[2 * it + 1] = (float)Q;
    body(s + 8,  A8);  loadC(s + 24, A8);
    body(s + 9,  A9);  loadC(s + 25, A9);
    body(s + 10, A10); loadC(s + 26, A10);
    body(s + 11, A11); loadC(s + 27, A11);
    body(s + 12, A12); loadC(s + 28, A12);
    body(s + 13, A13); loadC(s + 29, A13);
    body(s + 14, A14); loadC(s + 30, A14);
    body(s + 15, A15); loadC(s + 31, A15);
    renorm(s + 15);
  }
}

// ---------------------------------------------------------------------------
// Kernel 3.5: backward weights -> pair-plane 6-sub-plane layout
// w3D2[b][u][6][256]: sub-planes {row0:wd,wn,wr, row1:wd,wn,wr} of rows
// 2v..2v+1, u = v + lane.  bwd reads all 6 coalesced.  Reconstructs
// q = -Qep - log2(P); P(r,c) at pD2[b][(r>>1)+(c>>2)][(c>>2)*8+(r&1)*4+(c&3)].
// Epoch of (r,c): u = (r>>1)+(c>>2), epoch u>>3, lane c>>2.
// ---------------------------------------------------------------------------
__global__ void __launch_bounds__(256) weights_kernel(const float* __restrict__ pD2,
                                                      const float* __restrict__ Qep,
                                                      const float* __restrict__ costR,
                                                      float* __restrict__ w3D2) {
  int tid = blockIdx.x * 256 + threadIdx.x;   // = ((b*256 + r)*64 + l)
  int l = tid & 63;
  int r = (tid >> 6) & 255;
  int b = tid >> 14;
  const float* pbb = pD2 + (size_t)b * USTR * 512;
  const float* cbb = costR + (size_t)b * 65536;
  const float* qe0 = Qep + ((size_t)b * 64 + l) * 24;
  int rp = min(r + 1, 255);
  int c0i = 4 * l;
  int c4 = min(c0i + 4, 255);
  int lc4 = c4 >> 2;
  const float* qe1 = Qep + ((size_t)b * 64 + lc4) * 24;
  int u0 = (r >> 1) + l, u1r = (rp >> 1) + l;
  float P0a[5], P1a[5], c0a[5], c1a[5];
  ld4(P0a, pbb + (size_t)u0 * 512 + l * 8 + (r & 1) * 4);
  ld4(P1a, pbb + (size_t)u1r * 512 + l * 8 + (rp & 1) * 4);
  P0a[4] = pbb[(size_t)((r >> 1) + lc4) * 512 + lc4 * 8 + (r & 1) * 4 + (c4 & 3)];
  P1a[4] = pbb[(size_t)((rp >> 1) + lc4) * 512 + lc4 * 8 + (rp & 1) * 4 + (c4 & 3)];
  ld4(c0a, cbb + (size_t)r * 256 + c0i);  c0a[4] = cbb[(size_t)r * 256 + c4];
  ld4(c1a, cbb + (size_t)rp * 256 + c0i); c1a[4] = cbb[(size_t)rp * 256 + c4];
  float Q00 = qe0[u0 >> 3];
  float Q10 = qe0[u1r >> 3];
  float Q01 = qe1[((r >> 1) + lc4) >> 3];
  float Q11 = qe1[((rp >> 1) + lc4) >> 3];
  float q0a[5], q1a[5];
#pragma unroll
  for (int k = 0; k < 4; ++k) {
    q0a[k] = -Q00 - LOG2F(P0a[k]);
    q1a[k] = -Q10 - LOG2F(P1a[k]);
  }
  q0a[4] = -Q01 - LOG2F(P0a[4]);
  q1a[4] = -Q11 - LOG2F(P1a[4]);
  const float CL = 50.0f * 1.4426950408889634f;
  bool rm = (r < 255);
  float w[12];
#pragma unroll
  for (int k = 0; k < 4; ++k) {
    bool cm = (c0i + k < 255);
    float ad = fminf(fmaxf((q1a[k+1] - c1a[k+1]) - q0a[k], -CL), CL);
    float an = fminf(fmaxf((q1a[k]   - c1a[k])   - q0a[k], -CL), CL);
    float ar = fminf(fmaxf((q0a[k+1] - c0a[k+1]) - q0a[k], -CL), CL);
    w[k]     = (rm && cm) ? EXP2F(ad) : 0.0f;
    w[4 + k] = rm ? EXP2F(an) : 0.0f;
    w[8 + k] = cm ? EXP2F(ar) : 0.0f;
  }
  float* wp = w3D2 + ((size_t)b * USTR + u0) * 1536 + (r & 1) * 768 + c0i;
  *(float4*)(wp)       = *(float4*)(w);
  *(float4*)(wp + 256) = *(float4*)(w + 4);
  *(float4*)(wp + 512) = *(float4*)(w + 8);
}

// ---------------------------------------------------------------------------
// Kernel 4: backward recurrence, 2 ROWS PER SLOT, pair-plane weights.
// Lane l owns cols 4l..4l+3; at slot t processes rows R=2(190-t-l), R+1
// (active iff 0 <= t-(63-l) <= 127; lane 63 leads) -- 192 slots.  Plane
// u = 190-t: 6 coalesced 1 KB weight loads per slot (8-deep FIFO).
//   E[r][c] = E[r+1][c+1]*wd + E[r+1][c]*wn + E[r][c+1]*wr,  E[255][255]=1.
// E written row-major DIRECTLY to d_out (the one remaining scatter).
// ---------------------------------------------------------------------------
__global__ void __launch_bounds__(64, 1) bwd_kernel(const float* __restrict__ w3D2,
                                                    float* __restrict__ out) {
  int b = blockIdx.x, l = threadIdx.x;
  const float* wB = w3D2 + (size_t)b * USTR * 1536 + 4 * l;
  float* ob = out + (size_t)b * 65536 + 4 * l;
  float Ep0 = 0.f, Ep1 = 0.f, Ep2 = 0.f, Ep3 = 0.f;  // row R+2 (own)
  float top0 = 0.f, top1 = 0.f;  // my col-0 values of last pair (for lane l-1)
  float dcar = 0.f;              // E(R+2, 4l+4)
  float F0[24], F1[24], F2[24], F3[24], F4[24], F5[24], F6[24], F7[24];
  auto loadW = [&](int t, float* buf) {
    int u = 190 - t; u = u < 0 ? 0 : u;
    const float* p = wB + (size_t)u * 1536;
    ld4(buf,      p);        ld4(buf + 4,  p + 256);  ld4(buf + 8,  p + 512);
    ld4(buf + 12, p + 768);  ld4(buf + 16, p + 1024); ld4(buf + 20, p + 1280);
  };
  auto body = [&](int t, const float* w) {
    bool act = (unsigned)(t - (63 - l)) <= 127u;
    float rt0 = __shfl_down(top0, 1);   // E(R,   4l+4) from lane l+1
    float rt1 = __shfl_down(top1, 1);   // E(R+1, 4l+4)
    if (l == 63) { rt0 = 0.f; rt1 = 0.f; }
    // row R+1 (indices 12..23), cols 3 -> 0
    float u13 = w[15] * dcar + w[19] * Ep3 + w[23] * rt1;
    if (l == 63 && t == 0) u13 = 1.0f;          // seed E[255][255]
    float u12 = w[14] * Ep3 + w[18] * Ep2 + w[22] * u13;
    float u11 = w[13] * Ep2 + w[17] * Ep1 + w[21] * u12;
    float u10 = w[12] * Ep1 + w[16] * Ep0 + w[20] * u11;
    // row R (indices 0..11)
    float u03 = w[3] * rt1 + w[7] * u13 + w[11] * rt0;
    float u02 = w[2] * u13 + w[6] * u12 + w[10] * u03;
    float u01 = w[1] * u12 + w[5] * u11 + w[9]  * u02;
    float u00 = w[0] * u11 + w[4] * u10 + w[8]  * u01;
    if (act) {
      int R = 380 - 2 * t - 2 * l;
      *(float4*)(ob + (size_t)R * 256)       = (float4){u00, u01, u02, u03};
      *(float4*)(ob + (size_t)(R + 1) * 256) = (float4){u10, u11, u12, u13};
      Ep0 = u00; Ep1 = u01; Ep2 = u02; Ep3 = u03;
      top0 = u00; top1 = u10; dcar = rt0;
    }
  };
  loadW(0, F0); loadW(1, F1); loadW(2, F2); loadW(3, F3);
  loadW(4, F4); loadW(5, F5); loadW(6, F6); loadW(7, F7);
  for (int it = 0; it < 24; ++it) {   // 192 slots; last live slot = 190
    int s = it * 8;
    body(s + 0, F0); loadW(s + 8,  F0);
    body(s + 1, F1); loadW(s + 9,  F1);
    body(s + 2, F2); loadW(s + 10, F2);
    body(s + 3, F3); loadW(s + 11, F3);
    body(s + 4, F4); loadW(s + 12, F4);
    body(s + 5, F5); loadW(s + 13, F5);
    body(s + 6, F6); loadW(s + 14, F6);
    body(s + 7, F7); loadW(s + 15, F7);
  }
}

// ---------------------------------------------------------------------------
// Workspace (floats), ~18 MB:
//   rnx (2048) | rny (2048)
//   costR (8*65536, cost*ig2, row-major)
//   mD2   (8*192*512, exp2(-cost*ig2), pair-planes)
//   pD2   (8*192*512, p-domain mantissas, pair-planes)
//   Qep   (8*64*24, per-lane per-epoch scales)
//   w3D2  (8*192*1536, pair-plane packed weights)
// Alignment (E) goes straight into d_out from bwd_kernel.
// d_out: alignment [0 .. 524287], distance [524288 .. 524295].
// ---------------------------------------------------------------------------
extern "C" void kernel_launch(void* const* d_in, const int* in_sizes, int n_in,
                              void* d_out, int out_size, void* d_ws, size_t ws_size,
                              hipStream_t stream) {
  const float* x = (const float*)d_in[0];
  const float* y = (const float*)d_in[1];
  const float* gamma = (const float*)d_in[2];
  float* out = (float*)d_out;
  float* ws = (float*)d_ws;

  const size_t MAT  = (size_t)8 * 65536;
  const size_t PMAT = (size_t)8 * USTR * 512;
  float* rnx   = ws;
  float* rny   = ws + 2048;
  float* costR = ws + 4096;
  float* mD2   = costR + MAT;
  float* pD2   = mD2 + PMAT;
  float* Qep   = pD2 + PMAT;
  float* w3D2  = Qep + 12288;

  norms_kernel<<<1024, 256, 0, stream>>>(x, y, rnx, rny);
  cost_gemm<<<dim3(4, 8, 8), 256, 0, stream>>>(x, y, rnx, rny, gamma, costR, mD2);
  fwd_kernel<<<8, 64, 0, stream>>>(mD2, gamma, pD2, Qep, out + 524288);
  weights_kernel<<<512, 256, 0, stream>>>(pD2, Qep, costR, w3D2);
  bwd_kernel<<<8, 64, 0, stream>>>(w3D2, out);
}

// Round 19
// 125.543 us; speedup vs baseline: 1.3775x; 1.3775x over previous
//
#include <hip/hip_runtime.h>

// Problem constants: B=8, M=N=256, D=512
#define USTR 192   // pair-planes per batch-dir: u = (row>>1) + lane, 0..190

// Raw HW transcendentals: v_exp_f32 is 2^x, v_log_f32 is log2(x).
#define EXP2F(x) __builtin_amdgcn_exp2f(x)
#define LOG2F(x) __builtin_amdgcn_logf(x)

__device__ __forceinline__ void ld4(float d[4], const float* p) {
  float4 v = *(const float4*)p;
  d[0] = v.x; d[1] = v.y; d[2] = v.z; d[3] = v.w;
}

// ---------------------------------------------------------------------------
// Kernel 1: inverse row norms.  rn = 1 / max(||row||, 1e-8)
// ---------------------------------------------------------------------------
__global__ void __launch_bounds__(256) norms_kernel(const float* __restrict__ x,
                                                    const float* __restrict__ y,
                                                    float* __restrict__ rnx,
                                                    float* __restrict__ rny) {
  int g = blockIdx.x * 4 + (threadIdx.x >> 6);
  int lane = threadIdx.x & 63;
  const float* src; float* dst; int row;
  if (g < 2048) { src = x; dst = rnx; row = g; }
  else          { src = y; dst = rny; row = g - 2048; }
  const float* p = src + (size_t)row * 512;
  float4 v0 = *(const float4*)(p + lane * 4);
  float4 v1 = *(const float4*)(p + 256 + lane * 4);
  float s = v0.x*v0.x + v0.y*v0.y + v0.z*v0.z + v0.w*v0.w
          + v1.x*v1.x + v1.y*v1.y + v1.z*v1.z + v1.w*v1.w;
#pragma unroll
  for (int o = 32; o > 0; o >>= 1) s += __shfl_xor(s, o, 64);
  if (lane == 0) dst[row] = 1.0f / fmaxf(sqrtf(s), 1e-8f);
}

// ---------------------------------------------------------------------------
// Kernel 2: cost GEMM, 32x64 tiles (256 blocks).  Single logical output m =
// exp2(-cost*ig2), written TWICE in pair-plane layout:
//   forward copy  (batch-dir b):   plane u = v+l,    lane l,    rows 2v,2v+1
//   reversed copy (batch-dir 8+b): plane 190-u, lane 63-l, rows/cols reversed
// Each thread's 2x4 micro-tile is exactly one 8-float record.
// ---------------------------------------------------------------------------
__global__ void __launch_bounds__(256) cost_gemm(const float* __restrict__ x,
                                                 const float* __restrict__ y,
                                                 const float* __restrict__ rnx,
                                                 const float* __restrict__ rny,
                                                 const float* __restrict__ gamma,
                                                 float* __restrict__ mAll) {
  int b = blockIdx.z, mt = blockIdx.y, nt = blockIdx.x;
  int m0 = mt * 32, n0 = nt * 64;
  __shared__ float Xs[16][36];
  __shared__ float Ys[16][68];
  int tid = threadIdx.x;
  int row = tid >> 2, cq = tid & 3;
  int tx = tid & 15, ty = tid >> 4;
  const float* xb = x + ((size_t)b * 256 + m0) * 512;
  const float* yb = y + ((size_t)b * 256 + n0) * 512;
  float acc[2][4] = {};
  for (int k0 = 0; k0 < 512; k0 += 16) {
    float4 xv;
    if (tid < 128) xv = *(const float4*)(xb + (size_t)row * 512 + k0 + cq * 4);
    float4 yv = *(const float4*)(yb + (size_t)row * 512 + k0 + cq * 4);
    __syncthreads();
    if (tid < 128) {
      Xs[cq*4+0][row] = xv.x; Xs[cq*4+1][row] = xv.y;
      Xs[cq*4+2][row] = xv.z; Xs[cq*4+3][row] = xv.w;
    }
    Ys[cq*4+0][row] = yv.x; Ys[cq*4+1][row] = yv.y;
    Ys[cq*4+2][row] = yv.z; Ys[cq*4+3][row] = yv.w;
    __syncthreads();
#pragma unroll
    for (int kk = 0; kk < 16; ++kk) {
      float a0 = Xs[kk][ty * 2 + 0];
      float a1 = Xs[kk][ty * 2 + 1];
      float4 bv = *(const float4*)(&Ys[kk][tx * 4]);
      float br[4] = {bv.x, bv.y, bv.z, bv.w};
#pragma unroll
      for (int c = 0; c < 4; ++c) {
        acc[0][c] += a0 * br[c];
        acc[1][c] += a1 * br[c];
      }
    }
  }
  float gv = fmaxf(fabsf(gamma[0]), 1e-4f);
  float ig2 = 1.4426950408889634f / gv;
  float rx[2], ry[4];
#pragma unroll
  for (int r = 0; r < 2; ++r) rx[r] = rnx[b * 256 + m0 + ty * 2 + r];
#pragma unroll
  for (int c = 0; c < 4; ++c) ry[c] = rny[b * 256 + n0 + tx * 4 + c];
  int l = nt * 16 + tx;                  // column-group lane
  int v = mt * 16 + ty;                  // row-pair index
  int u = v + l;                         // pair-plane index
  float4 stm[2];
#pragma unroll
  for (int r = 0; r < 2; ++r) {
    float c0 = (1.0f - acc[r][0] * rx[r] * ry[0]) * ig2;
    float c1 = (1.0f - acc[r][1] * rx[r] * ry[1]) * ig2;
    float c2 = (1.0f - acc[r][2] * rx[r] * ry[2]) * ig2;
    float c3 = (1.0f - acc[r][3] * rx[r] * ry[3]) * ig2;
    stm[r] = (float4){EXP2F(-c0), EXP2F(-c1), EXP2F(-c2), EXP2F(-c3)};
  }
  float* mpF = mAll + ((size_t)b * USTR + u) * 512 + l * 8;
  *(float4*)(mpF)     = stm[0];
  *(float4*)(mpF + 4) = stm[1];
  float* mpR = mAll + ((size_t)(8 + b) * USTR + (190 - u)) * 512 + (63 - l) * 8;
  *(float4*)(mpR)     = (float4){stm[1].w, stm[1].z, stm[1].y, stm[1].x};
  *(float4*)(mpR + 4) = (float4){stm[0].w, stm[0].z, stm[0].y, stm[0].x};
}

// ---------------------------------------------------------------------------
// Kernel 3: dual-direction p-pass.  Blocks 0-7: forward p on batch b.
// Blocks 8-15: the SAME recurrence on the reversed m array = backward b-pass.
// One wave per block; lane l owns cols 4l..4l+3; slot t processes rows
// R=2(t-l), R+1 of plane u=t (active iff 0<=t-l<=127).  p = P * 2^Q, Q
// constant per 8-slot epoch (recorded in Qep, renorm at epoch end).
// Per slot: 3 shfl + 2 ldexp + 24 arith + coalesced 2 KB read + 2 KB write.
// E is recovered later as p*b/(m*Z) -- no weights, no log2 on the chain.
// ---------------------------------------------------------------------------
__global__ void __launch_bounds__(64, 1) pass_kernel(const float* __restrict__ mAll,
                                                     float* __restrict__ pAll,
                                                     float* __restrict__ QepAll,
                                                     const float* __restrict__ gamma,
                                                     float* __restrict__ dist_out) {
  int blk = blockIdx.x, l = threadIdx.x;
  int dir = blk >> 3, b = blk & 7;
  float gv = fmaxf(fabsf(gamma[0]), 1e-4f);
  float gl = gv * 0.6931471805599453f;      // R = q * gl
  const float* mb = mAll + (size_t)blk * USTR * 512 + l * 8;
  float* pb = pAll + (size_t)blk * USTR * 512 + l * 8;
  float* qe = QepAll + ((size_t)blk * 64 + l) * 24;
  float Pp0 = 0.f, Pp1 = 0.f, Pp2 = 0.f, Pp3 = 0.f;  // row R-1 (own, scaled)
  float bot0 = 0.f, bot1 = 0.f;   // my col-3 values of last pair (for lane l+1)
  int Q = 0;                       // lane scale: p = P * 2^Q
  float ucar = (l == 0) ? 1.0f : 0.f;  // p(R-1, 4l-1); origin seed p(-1,-1)=1
  float A0[8], A1[8], A2[8], A3[8], A4[8], A5[8], A6[8], A7[8];
  float A8[8], A9[8], A10[8], A11[8], A12[8], A13[8], A14[8], A15[8];
  auto loadC = [&](int t, float* buf) {
    int u = t > 190 ? 190 : t;
    const float* p = mb + (size_t)u * 512;
    ld4(buf, p); ld4(buf + 4, p + 4);
  };
  auto body = [&](int t, const float* mm) {
    bool act = (unsigned)(t - l) <= 127u;
    float s0 = __shfl_up(bot0, 1);   // p(R,   4l-1) from lane l-1
    float s1 = __shfl_up(bot1, 1);   // p(R+1, 4l-1)
    int  liQ = __shfl_up(Q, 1);
    if (l == 0) { s0 = 0.f; s1 = 0.f; }
    else { int adj = liQ - Q; s0 = ldexpf(s0, adj); s1 = ldexpf(s1, adj); }
    // row R
    float v0 = mm[0] * (Pp0 + s0 + ucar);
    float v1 = mm[1] * (Pp1 + v0 + Pp0);
    float v2 = mm[2] * (Pp2 + v1 + Pp1);
    float v3 = mm[3] * (Pp3 + v2 + Pp2);
    // row R+1
    float w0 = mm[4] * (v0 + s1 + s0);
    float w1 = mm[5] * (v1 + w0 + v0);
    float w2 = mm[6] * (v2 + w1 + v1);
    float w3 = mm[7] * (v3 + w2 + v2);
    if (act) {
      float* sp = pb + (size_t)t * 512;
      *(float4*)(sp)     = (float4){v0, v1, v2, v3};
      *(float4*)(sp + 4) = (float4){w0, w1, w2, w3};
      Pp0 = w0; Pp1 = w1; Pp2 = w2; Pp3 = w3;
      ucar = s1; bot0 = v3; bot1 = w3;
      if (dir == 0 && l == 63 && t == 190)
        dist_out[b] = (-(float)Q - LOG2F(w3)) * gl;   // distance, off-loop
    }
  };
  auto renorm = [&](int tEnd) {
    if ((unsigned)(tEnd - l) <= 127u) {
      int e = (int)((__float_as_uint(Pp3) >> 23) & 255u) - 127;
      Pp0 = ldexpf(Pp0, -e); Pp1 = ldexpf(Pp1, -e);
      Pp2 = ldexpf(Pp2, -e); Pp3 = ldexpf(Pp3, -e);
      ucar = ldexpf(ucar, -e);
      bot0 = ldexpf(bot0, -e); bot1 = ldexpf(bot1, -e);
      Q += e;
    }
  };
  loadC(0, A0);  loadC(1, A1);  loadC(2, A2);  loadC(3, A3);
  loadC(4, A4);  loadC(5, A5);  loadC(6, A6);  loadC(7, A7);
  loadC(8, A8);  loadC(9, A9);  loadC(10, A10); loadC(11, A11);
  loadC(12, A12); loadC(13, A13); loadC(14, A14); loadC(15, A15);
  for (int it = 0; it < 12; ++it) {   // 12 x 16 = 192 slots; last live 190
    int s = it * 16;
    qe[2 * it] = (float)Q;
    body(s + 0, A0); loadC(s + 16, A0);
    body(s + 1, A1); loadC(s + 17, A1);
    body(s + 2, A2); loadC(s + 18, A2);
    body(s + 3, A3); loadC(s + 19, A3);
    body(s + 4, A4); loadC(s + 20, A4);
    body(s + 5, A5); loadC(s + 21, A5);
    body(s + 6, A6); loadC(s + 22, A6);
    body(s + 7, A7); loadC(s + 23, A7);
    renorm(s + 7);
    qe[2 * it + 1] = (float)Q;
    body(s + 8,  A8);  loadC(s + 24, A8);
    body(s + 9,  A9);  loadC(s + 25, A9);
    body(s + 10, A10); loadC(s + 26, A10);
    body(s + 11, A11); loadC(s + 27, A11);
    body(s + 12, A12); loadC(s + 28, A12);
    body(s + 13, A13); loadC(s + 29, A13);
    body(s + 14, A14); loadC(s + 30, A14);
    body(s + 15, A15); loadC(s + 31, A15);
    renorm(s + 15);
  }
}

// ---------------------------------------------------------------------------
// Kernel 4: posterior combine.  E[r][c] = p(r,c) * b(r,c) / (m(r,c) * Z),
// Z = p(255,255).  Scales: p = P*2^Qf, b = B*2^Qb, Z = Zp*2^Zq ->
// E = (P*B)/(M*Zp) * 2^(Qf+Qb-Zq) via ldexp (underflow -> true-zero E).
// b(r,c) sits in the REVERSED pass output at plane 190-v-l, lane 63-l,
// half (1-r&1), element 3-k.  Writes row-major float4 directly to d_out.
// ---------------------------------------------------------------------------
__global__ void __launch_bounds__(256) e_kernel(const float* __restrict__ mAll,
                                                const float* __restrict__ pAll,
                                                const float* __restrict__ QepAll,
                                                float* __restrict__ out) {
  int tid = blockIdx.x * 256 + threadIdx.x;   // = ((b*256 + r)*64 + l)
  int l = tid & 63;
  int r = (tid >> 6) & 255;
  int b = tid >> 14;
  int v = r >> 1, rf = r & 1;
  int uF = v + l;
  int uR = 190 - v - l;
  const float* pF  = pAll + ((size_t)b * USTR + uF) * 512 + l * 8 + rf * 4;
  const float* pRv = pAll + ((size_t)(8 + b) * USTR + uR) * 512 + (63 - l) * 8 + (1 - rf) * 4;
  const float* mF  = mAll + ((size_t)b * USTR + uF) * 512 + l * 8 + rf * 4;
  float P[4], Bv[4], M[4];
  ld4(P, pF); ld4(Bv, pRv); ld4(M, mF);
  float Qf = QepAll[((size_t)b * 64 + l) * 24 + (uF >> 3)];
  float Qb = QepAll[((size_t)(8 + b) * 64 + (63 - l)) * 24 + (uR >> 3)];
  float Zp = pAll[((size_t)b * USTR + 190) * 512 + 511];
  float Zq = QepAll[((size_t)b * 64 + 63) * 24 + 23];
  int e = (int)(Qf + Qb - Zq);
  float inv = 1.0f / Zp;
  float4 o;
  o.x = ldexpf(P[0] * Bv[3] / M[0] * inv, e);
  o.y = ldexpf(P[1] * Bv[2] / M[1] * inv, e);
  o.z = ldexpf(P[2] * Bv[1] / M[2] * inv, e);
  o.w = ldexpf(P[3] * Bv[0] / M[3] * inv, e);
  *(float4*)(out + (size_t)b * 65536 + (size_t)r * 256 + 4 * l) = o;
}

// ---------------------------------------------------------------------------
// Workspace (floats), ~12.7 MB:
//   rnx (2048) | rny (2048)
//   mAll  (16*192*512: potentials, pair-planes; slots 0-7 fwd, 8-15 reversed)
//   pAll  (16*192*512: p-pass outputs, same layout)
//   QepAll (16*64*24: per-block per-lane per-epoch scales)
// Alignment (E) and distance go straight into d_out.
// d_out: alignment [0 .. 524287], distance [524288 .. 524295].
// ---------------------------------------------------------------------------
extern "C" void kernel_launch(void* const* d_in, const int* in_sizes, int n_in,
                              void* d_out, int out_size, void* d_ws, size_t ws_size,
                              hipStream_t stream) {
  const float* x = (const float*)d_in[0];
  const float* y = (const float*)d_in[1];
  const float* gamma = (const float*)d_in[2];
  float* out = (float*)d_out;
  float* ws = (float*)d_ws;

  const size_t PMAT = (size_t)16 * USTR * 512;
  float* rnx    = ws;
  float* rny    = ws + 2048;
  float* mAll   = ws + 4096;
  float* pAll   = mAll + PMAT;
  float* QepAll = pAll + PMAT;

  norms_kernel<<<1024, 256, 0, stream>>>(x, y, rnx, rny);
  cost_gemm<<<dim3(4, 8, 8), 256, 0, stream>>>(x, y, rnx, rny, gamma, mAll);
  pass_kernel<<<16, 64, 0, stream>>>(mAll, pAll, QepAll, gamma, out + 524288);
  e_kernel<<<512, 256, 0, stream>>>(mAll, pAll, QepAll, out);
}